// Round 7
// baseline (40.861 us; speedup 1.0000x reference)
//
#include <hip/hip_runtime.h>
#include <math.h>

// Problem constants
#define B_SZ   8192
#define D_IN   512
#define M0_N   128
#define M1_N   128
#define K_TOP  8
#define H_DIM  128
#define ROWS   8           // batch rows per compute block (1 row/thread)

// ws layout (ints):
//   [0..1]       idx_out  (top-2 modules of emb_out)
//   [64..1087]   pre1[col*8+r] : top-8 of emb1[task][:,col], all 128 cols
//   [2048..3071] pre0[col*8+r] : top-8 of emb0[task][:,col], all 128 cols

// ---------------------------------------------------------------------------
// Wave-parallel iterative top-k, jax.lax.top_k semantics (descending value,
// ties -> lowest index). NCH*64 candidates; lane 0 writes out_idx.
template<int NCH>
__device__ __forceinline__ void wave_topk(const float* __restrict__ base,
                                          int stride, int k, int* out_idx,
                                          int lane) {
  float v[NCH];
#pragma unroll
  for (int t = 0; t < NCH; ++t) v[t] = base[(t * 64 + lane) * stride];
  for (int r = 0; r < k; ++r) {
    float bv = -INFINITY;
    int bd = 0x7fffffff;
#pragma unroll
    for (int t = 0; t < NCH; ++t) {
      if (v[t] > bv) { bv = v[t]; bd = t * 64 + lane; }
    }
#pragma unroll
    for (int m = 1; m < 64; m <<= 1) {
      float ov = __shfl_xor(bv, m, 64);
      int   od = __shfl_xor(bd, m, 64);
      if (ov > bv || (ov == bv && od < bd)) { bv = ov; bd = od; }
    }
    if (lane == 0) out_idx[r] = bd;
    if ((bd & 63) == lane) {
      const int tw = bd >> 6;
#pragma unroll
      for (int tt = 0; tt < NCH; ++tt)
        if (tt == tw) v[tt] = -INFINITY;
    }
  }
}

// ---------------------------------------------------------------------------
// Speculative routing: top-8 for ALL columns of emb1 and emb0, one column per
// wave (256 waves chip-wide). Block(0,0) wave 0 also does emb_out top-2.
__global__ __launch_bounds__(256)
void route_pre(const int* __restrict__ task_id_p,
               const float* __restrict__ emb0,
               const float* __restrict__ emb1,
               const float* __restrict__ emb_out,
               int* __restrict__ ws) {
  const int task = task_id_p[0];
  const int lane = threadIdx.x & 63;
  const int wid  = threadIdx.x >> 6;
  const int col  = blockIdx.x * 4 + wid;
  if (blockIdx.y == 0) {
    wave_topk<2>(emb1 + (size_t)task * M0_N * M1_N + col, M1_N, K_TOP,
                 ws + 64 + col * 8, lane);
    if (blockIdx.x == 0 && wid == 0)
      wave_topk<2>(emb_out + task * M1_N, 1, 2, ws, lane);
  } else {
    wave_topk<8>(emb0 + (size_t)task * D_IN * M0_N + col, M0_N, K_TOP,
                 ws + 2048 + col * 8, lane);
  }
}

// ---------------------------------------------------------------------------
// Fused compute: layer0 (16 positional slots) + layer1 (2 modules) + sigmoid.
// Block = 8 rows x 256 threads; thread (g=tid&31, rl=tid>>5) owns hidden
// units 4g..4g+3 of row rl. 32-lane shfl_xor reduce per row.
// 1024 blocks -> 4 blocks/CU -> 4 waves/SIMD for latency hiding.
__global__ __launch_bounds__(256, 4)
void fused_compute(const float* __restrict__ x,
                   const float* __restrict__ W1_0, const float* __restrict__ b1_0,
                   const float* __restrict__ W2_0, const float* __restrict__ b2_0,
                   const float* __restrict__ W1_1, const float* __restrict__ b1_1,
                   const float* __restrict__ W2_1, const float* __restrict__ b2_1,
                   const int* __restrict__ ws, float* __restrict__ out) {
  __shared__ int   s_m1[2];
  __shared__ int   s_m0[16];
  __shared__ int   s_cols[128];
  __shared__ float tile[16 * 10];       // layer-0 outputs [slot][row], pad 10

  const int tid = threadIdx.x;
  const int rowbase = blockIdx.x * ROWS;

  // resolve routing indirection: per-thread dependent chain, ONE barrier
  if (tid < 128) {
    const int slot = tid >> 3, k = tid & 7;
    const int m1 = ws[slot >> 3];
    const int m0 = ws[64 + m1 * 8 + (slot & 7)];
    if (k == 0) s_m0[slot] = m0;
    s_cols[tid] = ws[2048 + m0 * 8 + k];
    if (tid < 2) s_m1[tid] = ws[tid];
  }
  __syncthreads();

  const int g  = tid & 31;              // h-group: units 4g..4g+3
  const int rl = tid >> 5;              // local row 0..7
  const int row = rowbase + rl;
  const float* xr = x + (size_t)row * D_IN;

  // ---- layer 0: 16 slots ----
  for (int s = 0; s < 16; ++s) {
    const int m0 = s_m0[s];
    const float4* w1p = (const float4*)(W1_0 + (size_t)m0 * (K_TOP * H_DIM));
    float4 w1v[8];
#pragma unroll
    for (int k = 0; k < 8; ++k) w1v[k] = w1p[k * 32 + g];
    const float4 b1v = ((const float4*)(b1_0 + m0 * H_DIM))[g];
    const float4 w2v = ((const float4*)(W2_0 + m0 * H_DIM))[g];
    const float  b2v = b2_0[m0];

    float xv[8];
#pragma unroll
    for (int k = 0; k < 8; ++k) xv[k] = xr[s_cols[s * 8 + k]];

    float4 h = b1v;
#pragma unroll
    for (int k = 0; k < 8; ++k) {
      h.x = fmaf(xv[k], w1v[k].x, h.x);
      h.y = fmaf(xv[k], w1v[k].y, h.y);
      h.z = fmaf(xv[k], w1v[k].z, h.z);
      h.w = fmaf(xv[k], w1v[k].w, h.w);
    }
    float p = 0.f;
    p = fmaf(fmaxf(h.x, 0.f), w2v.x, p);
    p = fmaf(fmaxf(h.y, 0.f), w2v.y, p);
    p = fmaf(fmaxf(h.z, 0.f), w2v.z, p);
    p = fmaf(fmaxf(h.w, 0.f), w2v.w, p);
#pragma unroll
    for (int m = 1; m < 32; m <<= 1) p += __shfl_xor(p, m, 64);
    if (g == 0) tile[s * 10 + rl] = p + b2v;
  }
  __syncthreads();

  // ---- layer 1 (2 modules) + sigmoid ----
#pragma unroll
  for (int j = 0; j < 2; ++j) {
    const int m1 = s_m1[j];
    const float4* w1p = (const float4*)(W1_1 + (size_t)m1 * (K_TOP * H_DIM));
    float4 w1v[8];
#pragma unroll
    for (int k = 0; k < 8; ++k) w1v[k] = w1p[k * 32 + g];
    const float4 b1v = ((const float4*)(b1_1 + m1 * H_DIM))[g];
    const float4 w2v = ((const float4*)(W2_1 + m1 * H_DIM))[g];
    const float  b2v = b2_1[m1];

    float xv[8];
#pragma unroll
    for (int k = 0; k < 8; ++k) xv[k] = tile[(j * 8 + k) * 10 + rl];

    float4 h = b1v;
#pragma unroll
    for (int k = 0; k < 8; ++k) {
      h.x = fmaf(xv[k], w1v[k].x, h.x);
      h.y = fmaf(xv[k], w1v[k].y, h.y);
      h.z = fmaf(xv[k], w1v[k].z, h.z);
      h.w = fmaf(xv[k], w1v[k].w, h.w);
    }
    float p = 0.f;
    p = fmaf(fmaxf(h.x, 0.f), w2v.x, p);
    p = fmaf(fmaxf(h.y, 0.f), w2v.y, p);
    p = fmaf(fmaxf(h.z, 0.f), w2v.z, p);
    p = fmaf(fmaxf(h.w, 0.f), w2v.w, p);
#pragma unroll
    for (int m = 1; m < 32; m <<= 1) p += __shfl_xor(p, m, 64);
    if (g == 0) {
      const float v = p + b2v;
      out[(size_t)row * 2 + j] = 1.f / (1.f + __expf(-v));
    }
  }
}

// ---------------------------------------------------------------------------
extern "C" void kernel_launch(void* const* d_in, const int* in_sizes, int n_in,
                              void* d_out, int out_size, void* d_ws, size_t ws_size,
                              hipStream_t stream) {
  const float* x       = (const float*)d_in[0];
  const int*   task_id = (const int*)  d_in[1];
  const float* emb0    = (const float*)d_in[2];
  const float* emb1    = (const float*)d_in[3];
  const float* emb_out = (const float*)d_in[4];
  const float* W1_0    = (const float*)d_in[5];
  const float* b1_0    = (const float*)d_in[6];
  const float* W2_0    = (const float*)d_in[7];
  const float* b2_0    = (const float*)d_in[8];
  const float* W1_1    = (const float*)d_in[9];
  const float* b1_1    = (const float*)d_in[10];
  const float* W2_1    = (const float*)d_in[11];
  const float* b2_1    = (const float*)d_in[12];

  int* ws = (int*)d_ws;

  route_pre<<<dim3(32, 2), 256, 0, stream>>>(task_id, emb0, emb1, emb_out, ws);
  fused_compute<<<B_SZ / ROWS, 256, 0, stream>>>(x, W1_0, b1_0, W2_0, b2_0,
                                                 W1_1, b1_1, W2_1, b2_1,
                                                 ws, (float*)d_out);
}

// Round 8
// 30.755 us; speedup vs baseline: 1.3286x; 1.3286x over previous
//
#include <hip/hip_runtime.h>
#include <math.h>

// Problem constants
#define B_SZ   8192
#define D_IN   512
#define M0_N   128
#define M1_N   128
#define K_TOP  8
#define H_DIM  128
#define ROWS   16          // batch rows per compute block

// ws layout (ints):
//   [0..1]       idx_out  (top-2 modules of emb_out)
//   [64..1087]   pre1[col*8+r] : top-8 of emb1[task][:,col], all 128 cols
//   [2048..3071] pre0[col*8+r] : top-8 of emb0[task][:,col], all 128 cols

// ---------------------------------------------------------------------------
// Wave-parallel iterative top-k, jax.lax.top_k semantics (descending value,
// ties -> lowest index). NCH*64 candidates; lane 0 writes out_idx.
template<int NCH>
__device__ __forceinline__ void wave_topk(const float* __restrict__ base,
                                          int stride, int k, int* out_idx,
                                          int lane) {
  float v[NCH];
#pragma unroll
  for (int t = 0; t < NCH; ++t) v[t] = base[(t * 64 + lane) * stride];
  for (int r = 0; r < k; ++r) {
    float bv = -INFINITY;
    int bd = 0x7fffffff;
#pragma unroll
    for (int t = 0; t < NCH; ++t) {
      if (v[t] > bv) { bv = v[t]; bd = t * 64 + lane; }
    }
#pragma unroll
    for (int m = 1; m < 64; m <<= 1) {
      float ov = __shfl_xor(bv, m, 64);
      int   od = __shfl_xor(bd, m, 64);
      if (ov > bv || (ov == bv && od < bd)) { bv = ov; bd = od; }
    }
    if (lane == 0) out_idx[r] = bd;
    if ((bd & 63) == lane) {
      const int tw = bd >> 6;
#pragma unroll
      for (int tt = 0; tt < NCH; ++tt)
        if (tt == tw) v[tt] = -INFINITY;
    }
  }
}

// ---------------------------------------------------------------------------
// Speculative routing: top-8 for ALL columns of emb1 and emb0, one column per
// wave (256 waves chip-wide). Block(0,0) wave 0 also does emb_out top-2.
__global__ __launch_bounds__(256)
void route_pre(const int* __restrict__ task_id_p,
               const float* __restrict__ emb0,
               const float* __restrict__ emb1,
               const float* __restrict__ emb_out,
               int* __restrict__ ws) {
  const int task = task_id_p[0];
  const int lane = threadIdx.x & 63;
  const int wid  = threadIdx.x >> 6;
  const int col  = blockIdx.x * 4 + wid;
  if (blockIdx.y == 0) {
    wave_topk<2>(emb1 + (size_t)task * M0_N * M1_N + col, M1_N, K_TOP,
                 ws + 64 + col * 8, lane);
    if (blockIdx.x == 0 && wid == 0)
      wave_topk<2>(emb_out + task * M1_N, 1, 2, ws, lane);
  } else {
    wave_topk<8>(emb0 + (size_t)task * D_IN * M0_N + col, M0_N, K_TOP,
                 ws + 2048 + col * 8, lane);
  }
}

// ---------------------------------------------------------------------------
// Fused compute: layer0 (16 positional slots, WAVE-SPECIALIZED: wave w owns
// slots 4w..4w+3, so each slot's weights are fetched by exactly one wave) +
// layer1 (2 modules) + sigmoid. Lane (g=lane&31, rh=lane>>5): hidden units
// 4g..4g+3, row parity rh; 8 row-pair iterations cover the block's 16 rows.
__global__ __launch_bounds__(256)
void fused_compute(const float* __restrict__ x,
                   const float* __restrict__ W1_0, const float* __restrict__ b1_0,
                   const float* __restrict__ W2_0, const float* __restrict__ b2_0,
                   const float* __restrict__ W1_1, const float* __restrict__ b1_1,
                   const float* __restrict__ W2_1, const float* __restrict__ b2_1,
                   const int* __restrict__ ws, float* __restrict__ out) {
  __shared__ int   s_m1[2];
  __shared__ int   s_m0[16];
  __shared__ int   s_cols[128];
  __shared__ float tile[16 * 18];       // layer-0 outputs [slot][row]

  const int tid = threadIdx.x;
  const int rowbase = blockIdx.x * ROWS;

  // resolve routing indirection: per-thread dependent chain, ONE barrier
  if (tid < 128) {
    const int slot = tid >> 3, k = tid & 7;
    const int m1 = ws[slot >> 3];
    const int m0 = ws[64 + m1 * 8 + (slot & 7)];
    if (k == 0) s_m0[slot] = m0;
    s_cols[tid] = ws[2048 + m0 * 8 + k];
    if (tid < 2) s_m1[tid] = ws[tid];
  }
  __syncthreads();

  const int wid  = tid >> 6;            // wave 0..3
  const int lane = tid & 63;
  const int g    = lane & 31;           // h-group: units 4g..4g+3
  const int rh   = lane >> 5;           // row parity within pair

  // ---- layer 0: wave w -> slots 4w..4w+3, loop over 16 rows ----
#pragma unroll
  for (int si = 0; si < 4; ++si) {
    const int s  = wid * 4 + si;
    const int m0 = s_m0[s];
    const float4* w1p = (const float4*)(W1_0 + (size_t)m0 * (K_TOP * H_DIM));
    float4 w1v[8];
#pragma unroll
    for (int k = 0; k < 8; ++k) w1v[k] = w1p[k * 32 + g];
    const float4 b1v = ((const float4*)(b1_0 + m0 * H_DIM))[g];
    const float4 w2v = ((const float4*)(W2_0 + m0 * H_DIM))[g];
    const float  b2v = b2_0[m0];
    int cols[8];
#pragma unroll
    for (int k = 0; k < 8; ++k) cols[k] = s_cols[s * 8 + k];

#pragma unroll
    for (int rp = 0; rp < 8; ++rp) {
      const int r = rp * 2 + rh;
      const float* xr = x + (size_t)(rowbase + r) * D_IN;
      float xv[8];
#pragma unroll
      for (int k = 0; k < 8; ++k) xv[k] = xr[cols[k]];

      float4 h = b1v;
#pragma unroll
      for (int k = 0; k < 8; ++k) {
        h.x = fmaf(xv[k], w1v[k].x, h.x);
        h.y = fmaf(xv[k], w1v[k].y, h.y);
        h.z = fmaf(xv[k], w1v[k].z, h.z);
        h.w = fmaf(xv[k], w1v[k].w, h.w);
      }
      float p = 0.f;
      p = fmaf(fmaxf(h.x, 0.f), w2v.x, p);
      p = fmaf(fmaxf(h.y, 0.f), w2v.y, p);
      p = fmaf(fmaxf(h.z, 0.f), w2v.z, p);
      p = fmaf(fmaxf(h.w, 0.f), w2v.w, p);
#pragma unroll
      for (int m = 1; m < 32; m <<= 1) p += __shfl_xor(p, m, 64);
      if (g == 0) tile[s * 18 + r] = p + b2v;
    }
  }
  __syncthreads();

  // ---- layer 1 (2 modules) + sigmoid: thread (g, rl) rows {2rl, 2rl+1} ----
  const int rl = tid >> 5;              // row pair 0..7 (g = tid&31 == g above)
  const int r0 = rl * 2, r1 = r0 + 1;
#pragma unroll
  for (int j = 0; j < 2; ++j) {
    const int m1 = s_m1[j];
    const float4* w1p = (const float4*)(W1_1 + (size_t)m1 * (K_TOP * H_DIM));
    float4 w1v[8];
#pragma unroll
    for (int k = 0; k < 8; ++k) w1v[k] = w1p[k * 32 + g];
    const float4 b1v = ((const float4*)(b1_1 + m1 * H_DIM))[g];
    const float4 w2v = ((const float4*)(W2_1 + m1 * H_DIM))[g];
    const float  b2v = b2_1[m1];

    float xv0[8], xv1[8];
#pragma unroll
    for (int k = 0; k < 8; ++k) {
      xv0[k] = tile[(j * 8 + k) * 18 + r0];
      xv1[k] = tile[(j * 8 + k) * 18 + r1];
    }
    float4 h0 = b1v, h1 = b1v;
#pragma unroll
    for (int k = 0; k < 8; ++k) {
      h0.x = fmaf(xv0[k], w1v[k].x, h0.x);
      h0.y = fmaf(xv0[k], w1v[k].y, h0.y);
      h0.z = fmaf(xv0[k], w1v[k].z, h0.z);
      h0.w = fmaf(xv0[k], w1v[k].w, h0.w);
      h1.x = fmaf(xv1[k], w1v[k].x, h1.x);
      h1.y = fmaf(xv1[k], w1v[k].y, h1.y);
      h1.z = fmaf(xv1[k], w1v[k].z, h1.z);
      h1.w = fmaf(xv1[k], w1v[k].w, h1.w);
    }
    float p0 = 0.f, p1 = 0.f;
    p0 = fmaf(fmaxf(h0.x, 0.f), w2v.x, p0);
    p0 = fmaf(fmaxf(h0.y, 0.f), w2v.y, p0);
    p0 = fmaf(fmaxf(h0.z, 0.f), w2v.z, p0);
    p0 = fmaf(fmaxf(h0.w, 0.f), w2v.w, p0);
    p1 = fmaf(fmaxf(h1.x, 0.f), w2v.x, p1);
    p1 = fmaf(fmaxf(h1.y, 0.f), w2v.y, p1);
    p1 = fmaf(fmaxf(h1.z, 0.f), w2v.z, p1);
    p1 = fmaf(fmaxf(h1.w, 0.f), w2v.w, p1);
#pragma unroll
    for (int m = 1; m < 32; m <<= 1) {
      p0 += __shfl_xor(p0, m, 64);
      p1 += __shfl_xor(p1, m, 64);
    }
    if (g == 0) {
      const float v0 = p0 + b2v;
      const float v1 = p1 + b2v;
      out[(size_t)(rowbase + r0) * 2 + j] = 1.f / (1.f + __expf(-v0));
      out[(size_t)(rowbase + r1) * 2 + j] = 1.f / (1.f + __expf(-v1));
    }
  }
}

// ---------------------------------------------------------------------------
extern "C" void kernel_launch(void* const* d_in, const int* in_sizes, int n_in,
                              void* d_out, int out_size, void* d_ws, size_t ws_size,
                              hipStream_t stream) {
  const float* x       = (const float*)d_in[0];
  const int*   task_id = (const int*)  d_in[1];
  const float* emb0    = (const float*)d_in[2];
  const float* emb1    = (const float*)d_in[3];
  const float* emb_out = (const float*)d_in[4];
  const float* W1_0    = (const float*)d_in[5];
  const float* b1_0    = (const float*)d_in[6];
  const float* W2_0    = (const float*)d_in[7];
  const float* b2_0    = (const float*)d_in[8];
  const float* W1_1    = (const float*)d_in[9];
  const float* b1_1    = (const float*)d_in[10];
  const float* W2_1    = (const float*)d_in[11];
  const float* b2_1    = (const float*)d_in[12];

  int* ws = (int*)d_ws;

  route_pre<<<dim3(32, 2), 256, 0, stream>>>(task_id, emb0, emb1, emb_out, ws);
  fused_compute<<<B_SZ / ROWS, 256, 0, stream>>>(x, W1_0, b1_0, W2_0, b2_0,
                                                 W1_1, b1_1, W2_1, b2_1,
                                                 ws, (float*)d_out);
}

// Round 9
// 28.486 us; speedup vs baseline: 1.4344x; 1.0797x over previous
//
#include <hip/hip_runtime.h>
#include <math.h>

// Problem constants
#define B_SZ   8192
#define D_IN   512
#define M0_N   128
#define M1_N   128
#define K_TOP  8
#define H_DIM  128
#define ROWS   16          // batch rows per compute block
#define XP     520         // LDS x-tile row pitch (floats)

// ws layout (ints):
//   [0..1]       idx_out  (top-2 modules of emb_out)
//   [64..1087]   pre1[col*8+r] : top-8 of emb1[task][:,col], all 128 cols
//   [2048..3071] pre0[col*8+r] : top-8 of emb0[task][:,col], all 128 cols

// ---------------------------------------------------------------------------
// Wave-parallel iterative top-k, jax.lax.top_k semantics (descending value,
// ties -> lowest index). NCH*64 candidates; lane 0 writes out_idx.
template<int NCH>
__device__ __forceinline__ void wave_topk(const float* __restrict__ base,
                                          int stride, int k, int* out_idx,
                                          int lane) {
  float v[NCH];
#pragma unroll
  for (int t = 0; t < NCH; ++t) v[t] = base[(t * 64 + lane) * stride];
  for (int r = 0; r < k; ++r) {
    float bv = -INFINITY;
    int bd = 0x7fffffff;
#pragma unroll
    for (int t = 0; t < NCH; ++t) {
      if (v[t] > bv) { bv = v[t]; bd = t * 64 + lane; }
    }
#pragma unroll
    for (int m = 1; m < 64; m <<= 1) {
      float ov = __shfl_xor(bv, m, 64);
      int   od = __shfl_xor(bd, m, 64);
      if (ov > bv || (ov == bv && od < bd)) { bv = ov; bd = od; }
    }
    if (lane == 0) out_idx[r] = bd;
    if ((bd & 63) == lane) {
      const int tw = bd >> 6;
#pragma unroll
      for (int tt = 0; tt < NCH; ++tt)
        if (tt == tw) v[tt] = -INFINITY;
    }
  }
}

// ---------------------------------------------------------------------------
// Speculative routing: top-8 for ALL columns of emb1 and emb0, one column per
// wave (256 waves chip-wide). Block(0,0) wave 0 also does emb_out top-2.
__global__ __launch_bounds__(256)
void route_pre(const int* __restrict__ task_id_p,
               const float* __restrict__ emb0,
               const float* __restrict__ emb1,
               const float* __restrict__ emb_out,
               int* __restrict__ ws) {
  const int task = task_id_p[0];
  const int lane = threadIdx.x & 63;
  const int wid  = threadIdx.x >> 6;
  const int col  = blockIdx.x * 4 + wid;
  if (blockIdx.y == 0) {
    wave_topk<2>(emb1 + (size_t)task * M0_N * M1_N + col, M1_N, K_TOP,
                 ws + 64 + col * 8, lane);
    if (blockIdx.x == 0 && wid == 0)
      wave_topk<2>(emb_out + task * M1_N, 1, 2, ws, lane);
  } else {
    wave_topk<8>(emb0 + (size_t)task * D_IN * M0_N + col, M0_N, K_TOP,
                 ws + 2048 + col * 8, lane);
  }
}

// ---------------------------------------------------------------------------
// Fused compute. Key fix vs R8: the block's full 16x512 x-tile is staged into
// LDS with coalesced float4 loads FIRST (HBM latency paid once per block, and
// overlapped with the routing-resolution chain); layer-0's scattered gathers
// then hit LDS (broadcast, conflict-free) instead of taking an HBM-cold miss
// per (row,col). Layer0 wave-specialized (wave w -> slots 4w..4w+3, weights
// register-stationary, fetched once); layer1 (2 modules) + sigmoid fused.
__global__ __launch_bounds__(256)
void fused_compute(const float* __restrict__ x,
                   const float* __restrict__ W1_0, const float* __restrict__ b1_0,
                   const float* __restrict__ W2_0, const float* __restrict__ b2_0,
                   const float* __restrict__ W1_1, const float* __restrict__ b1_1,
                   const float* __restrict__ W2_1, const float* __restrict__ b2_1,
                   const int* __restrict__ ws, float* __restrict__ out) {
  __shared__ float xt[ROWS * XP];       // 33.3 KB x-tile
  __shared__ int   s_m1[2];
  __shared__ int   s_m0[16];
  __shared__ int   s_cols[128];
  __shared__ float tile[16 * 18];       // layer-0 outputs [slot][row]

  const int tid = threadIdx.x;
  const int rowbase = blockIdx.x * ROWS;

  // ---- issue the coalesced x-tile loads (fills the memory pipe early) ----
  float4 xr[8];
#pragma unroll
  for (int i = 0; i < 8; ++i) {
    const int e = tid + i * 256;        // float4 index: row = e>>7, col4 = e&127
    xr[i] = *(const float4*)(x + (size_t)(rowbase + (e >> 7)) * D_IN +
                             (e & 127) * 4);
  }

  // ---- routing resolution (dependent L2 chain, overlaps the x loads) ----
  if (tid < 128) {
    const int slot = tid >> 3, k = tid & 7;
    const int m1 = ws[slot >> 3];
    const int m0 = ws[64 + m1 * 8 + (slot & 7)];
    if (k == 0) s_m0[slot] = m0;
    s_cols[tid] = ws[2048 + m0 * 8 + k];
    if (tid < 2) s_m1[tid] = ws[tid];
  }

  // ---- park x tile in LDS ----
#pragma unroll
  for (int i = 0; i < 8; ++i) {
    const int e = tid + i * 256;
    *(float4*)(xt + (e >> 7) * XP + (e & 127) * 4) = xr[i];
  }
  __syncthreads();

  const int wid  = tid >> 6;            // wave 0..3
  const int lane = tid & 63;
  const int g    = lane & 31;           // h-group: units 4g..4g+3
  const int rh   = lane >> 5;           // row parity within pair

  // ---- layer 0: wave w -> slots 4w..4w+3, loop over 16 rows ----
#pragma unroll
  for (int si = 0; si < 4; ++si) {
    const int s  = wid * 4 + si;
    const int m0 = s_m0[s];
    const float4* w1p = (const float4*)(W1_0 + (size_t)m0 * (K_TOP * H_DIM));
    float4 w1v[8];
#pragma unroll
    for (int k = 0; k < 8; ++k) w1v[k] = w1p[k * 32 + g];
    const float4 b1v = ((const float4*)(b1_0 + m0 * H_DIM))[g];
    const float4 w2v = ((const float4*)(W2_0 + m0 * H_DIM))[g];
    const float  b2v = b2_0[m0];
    int cols[8];
#pragma unroll
    for (int k = 0; k < 8; ++k) cols[k] = s_cols[s * 8 + k];

#pragma unroll
    for (int rp = 0; rp < 8; ++rp) {
      const int r = rp * 2 + rh;
      const float* xrow = xt + r * XP;
      float xv[8];
#pragma unroll
      for (int k = 0; k < 8; ++k) xv[k] = xrow[cols[k]];

      float4 h = b1v;
#pragma unroll
      for (int k = 0; k < 8; ++k) {
        h.x = fmaf(xv[k], w1v[k].x, h.x);
        h.y = fmaf(xv[k], w1v[k].y, h.y);
        h.z = fmaf(xv[k], w1v[k].z, h.z);
        h.w = fmaf(xv[k], w1v[k].w, h.w);
      }
      float p = 0.f;
      p = fmaf(fmaxf(h.x, 0.f), w2v.x, p);
      p = fmaf(fmaxf(h.y, 0.f), w2v.y, p);
      p = fmaf(fmaxf(h.z, 0.f), w2v.z, p);
      p = fmaf(fmaxf(h.w, 0.f), w2v.w, p);
#pragma unroll
      for (int m = 1; m < 32; m <<= 1) p += __shfl_xor(p, m, 64);
      if (g == 0) tile[s * 18 + r] = p + b2v;
    }
  }
  __syncthreads();

  // ---- layer 1 (2 modules) + sigmoid: thread (g, rl) rows {2rl, 2rl+1} ----
  const int rl = tid >> 5;              // row pair 0..7
  const int r0 = rl * 2, r1 = r0 + 1;
#pragma unroll
  for (int j = 0; j < 2; ++j) {
    const int m1 = s_m1[j];
    const float4* w1p = (const float4*)(W1_1 + (size_t)m1 * (K_TOP * H_DIM));
    float4 w1v[8];
#pragma unroll
    for (int k = 0; k < 8; ++k) w1v[k] = w1p[k * 32 + g];
    const float4 b1v = ((const float4*)(b1_1 + m1 * H_DIM))[g];
    const float4 w2v = ((const float4*)(W2_1 + m1 * H_DIM))[g];
    const float  b2v = b2_1[m1];

    float xv0[8], xv1[8];
#pragma unroll
    for (int k = 0; k < 8; ++k) {
      xv0[k] = tile[(j * 8 + k) * 18 + r0];
      xv1[k] = tile[(j * 8 + k) * 18 + r1];
    }
    float4 h0 = b1v, h1 = b1v;
#pragma unroll
    for (int k = 0; k < 8; ++k) {
      h0.x = fmaf(xv0[k], w1v[k].x, h0.x);
      h0.y = fmaf(xv0[k], w1v[k].y, h0.y);
      h0.z = fmaf(xv0[k], w1v[k].z, h0.z);
      h0.w = fmaf(xv0[k], w1v[k].w, h0.w);
      h1.x = fmaf(xv1[k], w1v[k].x, h1.x);
      h1.y = fmaf(xv1[k], w1v[k].y, h1.y);
      h1.z = fmaf(xv1[k], w1v[k].z, h1.z);
      h1.w = fmaf(xv1[k], w1v[k].w, h1.w);
    }
    float p0 = 0.f, p1 = 0.f;
    p0 = fmaf(fmaxf(h0.x, 0.f), w2v.x, p0);
    p0 = fmaf(fmaxf(h0.y, 0.f), w2v.y, p0);
    p0 = fmaf(fmaxf(h0.z, 0.f), w2v.z, p0);
    p0 = fmaf(fmaxf(h0.w, 0.f), w2v.w, p0);
    p1 = fmaf(fmaxf(h1.x, 0.f), w2v.x, p1);
    p1 = fmaf(fmaxf(h1.y, 0.f), w2v.y, p1);
    p1 = fmaf(fmaxf(h1.z, 0.f), w2v.z, p1);
    p1 = fmaf(fmaxf(h1.w, 0.f), w2v.w, p1);
#pragma unroll
    for (int m = 1; m < 32; m <<= 1) {
      p0 += __shfl_xor(p0, m, 64);
      p1 += __shfl_xor(p1, m, 64);
    }
    if (g == 0) {
      const float v0 = p0 + b2v;
      const float v1 = p1 + b2v;
      out[(size_t)(rowbase + r0) * 2 + j] = 1.f / (1.f + __expf(-v0));
      out[(size_t)(rowbase + r1) * 2 + j] = 1.f / (1.f + __expf(-v1));
    }
  }
}

// ---------------------------------------------------------------------------
extern "C" void kernel_launch(void* const* d_in, const int* in_sizes, int n_in,
                              void* d_out, int out_size, void* d_ws, size_t ws_size,
                              hipStream_t stream) {
  const float* x       = (const float*)d_in[0];
  const int*   task_id = (const int*)  d_in[1];
  const float* emb0    = (const float*)d_in[2];
  const float* emb1    = (const float*)d_in[3];
  const float* emb_out = (const float*)d_in[4];
  const float* W1_0    = (const float*)d_in[5];
  const float* b1_0    = (const float*)d_in[6];
  const float* W2_0    = (const float*)d_in[7];
  const float* b2_0    = (const float*)d_in[8];
  const float* W1_1    = (const float*)d_in[9];
  const float* b1_1    = (const float*)d_in[10];
  const float* W2_1    = (const float*)d_in[11];
  const float* b2_1    = (const float*)d_in[12];

  int* ws = (int*)d_ws;

  route_pre<<<dim3(32, 2), 256, 0, stream>>>(task_id, emb0, emb1, emb_out, ws);
  fused_compute<<<B_SZ / ROWS, 256, 0, stream>>>(x, W1_0, b1_0, W2_0, b2_0,
                                                 W1_1, b1_1, W2_1, b2_1,
                                                 ws, (float*)d_out);
}

// Round 10
// 24.158 us; speedup vs baseline: 1.6914x; 1.1791x over previous
//
#include <hip/hip_runtime.h>
#include <math.h>

// Problem constants
#define B_SZ   8192
#define D_IN   512
#define M0_N   128
#define M1_N   128
#define K_TOP  8
#define H_DIM  128
#define ROWS   16          // batch rows per compute block
#define XP     520         // LDS x-tile row pitch (floats)

// ws layout (ints):
//   [0..1]       idx_out  (top-2 modules of emb_out)
//   [64..1087]   pre1[col*8+r] : top-8 of emb1[task][:,col], all 128 cols
//   [2048..3071] pre0[col*8+r] : top-8 of emb0[task][:,col], all 128 cols

// ---------------------------------------------------------------------------
// Wave-parallel iterative top-k, jax.lax.top_k semantics (descending value,
// ties -> lowest index). NCH*64 candidates; lane 0 writes out_idx.
template<int NCH>
__device__ __forceinline__ void wave_topk(const float* __restrict__ base,
                                          int stride, int k, int* out_idx,
                                          int lane) {
  float v[NCH];
#pragma unroll
  for (int t = 0; t < NCH; ++t) v[t] = base[(t * 64 + lane) * stride];
  for (int r = 0; r < k; ++r) {
    float bv = -INFINITY;
    int bd = 0x7fffffff;
#pragma unroll
    for (int t = 0; t < NCH; ++t) {
      if (v[t] > bv) { bv = v[t]; bd = t * 64 + lane; }
    }
#pragma unroll
    for (int m = 1; m < 64; m <<= 1) {
      float ov = __shfl_xor(bv, m, 64);
      int   od = __shfl_xor(bd, m, 64);
      if (ov > bv || (ov == bv && od < bd)) { bv = ov; bd = od; }
    }
    if (lane == 0) out_idx[r] = bd;
    if ((bd & 63) == lane) {
      const int tw = bd >> 6;
#pragma unroll
      for (int tt = 0; tt < NCH; ++tt)
        if (tt == tw) v[tt] = -INFINITY;
    }
  }
}

// ---------------------------------------------------------------------------
// Speculative routing: top-8 for ALL columns of emb1 and emb0, one column per
// wave (256 waves chip-wide). Block(0,0) wave 0 also does emb_out top-2.
__global__ __launch_bounds__(256)
void route_pre(const int* __restrict__ task_id_p,
               const float* __restrict__ emb0,
               const float* __restrict__ emb1,
               const float* __restrict__ emb_out,
               int* __restrict__ ws) {
  const int task = task_id_p[0];
  const int lane = threadIdx.x & 63;
  const int wid  = threadIdx.x >> 6;
  const int col  = blockIdx.x * 4 + wid;
  if (blockIdx.y == 0) {
    wave_topk<2>(emb1 + (size_t)task * M0_N * M1_N + col, M1_N, K_TOP,
                 ws + 64 + col * 8, lane);
    if (blockIdx.x == 0 && wid == 0)
      wave_topk<2>(emb_out + task * M1_N, 1, 2, ws, lane);
  } else {
    wave_topk<8>(emb0 + (size_t)task * D_IN * M0_N + col, M0_N, K_TOP,
                 ws + 2048 + col * 8, lane);
  }
}

// ---------------------------------------------------------------------------
// 16-lane sum reduce entirely on the VALU pipe via DPP (no DS ops):
// quad_perm xor1 (0xB1), quad_perm xor2 (0x4E), row_ror:4 (0x124),
// row_ror:8 (0x128). After these, all 16 lanes of each row-group hold the sum.
__device__ __forceinline__ float dpp_add16(float p) {
  int t;
  t = __builtin_amdgcn_update_dpp(0, __float_as_int(p), 0xB1, 0xF, 0xF, true);
  p += __int_as_float(t);
  t = __builtin_amdgcn_update_dpp(0, __float_as_int(p), 0x4E, 0xF, 0xF, true);
  p += __int_as_float(t);
  t = __builtin_amdgcn_update_dpp(0, __float_as_int(p), 0x124, 0xF, 0xF, true);
  p += __int_as_float(t);
  t = __builtin_amdgcn_update_dpp(0, __float_as_int(p), 0x128, 0xF, 0xF, true);
  p += __int_as_float(t);
  return p;
}

// Per-thread 8-hidden-unit MLP slice + DPP reduce. Lane (g=lane&15, rq).
__device__ __forceinline__ float slice8(const float4* w1a, const float4* w1b,
                                        const float4& b1a, const float4& b1b,
                                        const float4& w2a, const float4& w2b,
                                        const float* xv) {
  float4 h0 = b1a, h1 = b1b;
#pragma unroll
  for (int k = 0; k < 8; ++k) {
    h0.x = fmaf(xv[k], w1a[k].x, h0.x);
    h0.y = fmaf(xv[k], w1a[k].y, h0.y);
    h0.z = fmaf(xv[k], w1a[k].z, h0.z);
    h0.w = fmaf(xv[k], w1a[k].w, h0.w);
    h1.x = fmaf(xv[k], w1b[k].x, h1.x);
    h1.y = fmaf(xv[k], w1b[k].y, h1.y);
    h1.z = fmaf(xv[k], w1b[k].z, h1.z);
    h1.w = fmaf(xv[k], w1b[k].w, h1.w);
  }
  float pa = 0.f, pb = 0.f;
  pa = fmaf(fmaxf(h0.x, 0.f), w2a.x, pa);
  pa = fmaf(fmaxf(h0.y, 0.f), w2a.y, pa);
  pa = fmaf(fmaxf(h0.z, 0.f), w2a.z, pa);
  pa = fmaf(fmaxf(h0.w, 0.f), w2a.w, pa);
  pb = fmaf(fmaxf(h1.x, 0.f), w2b.x, pb);
  pb = fmaf(fmaxf(h1.y, 0.f), w2b.y, pb);
  pb = fmaf(fmaxf(h1.z, 0.f), w2b.z, pb);
  pb = fmaf(fmaxf(h1.w, 0.f), w2b.w, pb);
  return dpp_add16(pa + pb);
}

// ---------------------------------------------------------------------------
// Fused compute. vs R9: reduce groups are 16 lanes (thread owns 8 h-units),
// so the cross-lane reduce is 4 DPP VALU adds — ZERO ds_swizzle ops. Lane
// mapping: g=lane&15 (h-units 8g..8g+7), rq=lane>>4 (row within iter-group).
// Layer0 wave-specialized (wave w -> slots 4w..4w+3), x from the LDS tile.
__global__ __launch_bounds__(256)
void fused_compute(const float* __restrict__ x,
                   const float* __restrict__ W1_0, const float* __restrict__ b1_0,
                   const float* __restrict__ W2_0, const float* __restrict__ b2_0,
                   const float* __restrict__ W1_1, const float* __restrict__ b1_1,
                   const float* __restrict__ W2_1, const float* __restrict__ b2_1,
                   const int* __restrict__ ws, float* __restrict__ out) {
  __shared__ float xt[ROWS * XP];       // 33.3 KB x-tile
  __shared__ int   s_m1[2];
  __shared__ int   s_m0[16];
  __shared__ int   s_cols[128];
  __shared__ float tile[16 * 18];       // layer-0 outputs [slot][row]

  const int tid = threadIdx.x;
  const int rowbase = blockIdx.x * ROWS;

  // ---- issue the coalesced x-tile loads (fills the memory pipe early) ----
  float4 xr[8];
#pragma unroll
  for (int i = 0; i < 8; ++i) {
    const int e = tid + i * 256;
    xr[i] = *(const float4*)(x + (size_t)(rowbase + (e >> 7)) * D_IN +
                             (e & 127) * 4);
  }

  // ---- routing resolution (dependent L2 chain, overlaps the x loads) ----
  if (tid < 128) {
    const int slot = tid >> 3, k = tid & 7;
    const int m1 = ws[slot >> 3];
    const int m0 = ws[64 + m1 * 8 + (slot & 7)];
    if (k == 0) s_m0[slot] = m0;
    s_cols[tid] = ws[2048 + m0 * 8 + k];
    if (tid < 2) s_m1[tid] = ws[tid];
  }

  // ---- park x tile in LDS ----
#pragma unroll
  for (int i = 0; i < 8; ++i) {
    const int e = tid + i * 256;
    *(float4*)(xt + (e >> 7) * XP + (e & 127) * 4) = xr[i];
  }
  __syncthreads();

  const int wid  = tid >> 6;            // wave 0..3
  const int lane = tid & 63;
  const int g    = lane & 15;           // h-group: units 8g..8g+7
  const int rq   = lane >> 4;           // row-in-group 0..3

  // ---- layer 0: wave w -> slots 4w..4w+3; 4 iters x 4 rows = 16 rows ----
#pragma unroll
  for (int si = 0; si < 4; ++si) {
    const int s  = wid * 4 + si;
    const int m0 = s_m0[s];
    const float4* w1p = (const float4*)(W1_0 + (size_t)m0 * (K_TOP * H_DIM));
    float4 w1a[8], w1b[8];
#pragma unroll
    for (int k = 0; k < 8; ++k) {
      w1a[k] = w1p[k * 32 + 2 * g];
      w1b[k] = w1p[k * 32 + 2 * g + 1];
    }
    const float4 b1a = ((const float4*)(b1_0 + m0 * H_DIM))[2 * g];
    const float4 b1b = ((const float4*)(b1_0 + m0 * H_DIM))[2 * g + 1];
    const float4 w2a = ((const float4*)(W2_0 + m0 * H_DIM))[2 * g];
    const float4 w2b = ((const float4*)(W2_0 + m0 * H_DIM))[2 * g + 1];
    const float  b2v = b2_0[m0];
    int cols[8];
#pragma unroll
    for (int k = 0; k < 8; ++k) cols[k] = s_cols[s * 8 + k];

#pragma unroll
    for (int it = 0; it < 4; ++it) {
      const int r = it * 4 + rq;
      const float* xrow = xt + r * XP;
      float xv[8];
#pragma unroll
      for (int k = 0; k < 8; ++k) xv[k] = xrow[cols[k]];
      const float p = slice8(w1a, w1b, b1a, b1b, w2a, w2b, xv);
      if (g == 0) tile[s * 18 + r] = p + b2v;
    }
  }
  __syncthreads();

  // ---- layer 1: wave w -> module j=w&1, row-half w>>1; + sigmoid ----
  {
    const int j  = wid & 1;
    const int rh = wid >> 1;
    const int m1 = s_m1[j];
    const float4* w1p = (const float4*)(W1_1 + (size_t)m1 * (K_TOP * H_DIM));
    float4 w1a[8], w1b[8];
#pragma unroll
    for (int k = 0; k < 8; ++k) {
      w1a[k] = w1p[k * 32 + 2 * g];
      w1b[k] = w1p[k * 32 + 2 * g + 1];
    }
    const float4 b1a = ((const float4*)(b1_1 + m1 * H_DIM))[2 * g];
    const float4 b1b = ((const float4*)(b1_1 + m1 * H_DIM))[2 * g + 1];
    const float4 w2a = ((const float4*)(W2_1 + m1 * H_DIM))[2 * g];
    const float4 w2b = ((const float4*)(W2_1 + m1 * H_DIM))[2 * g + 1];
    const float  b2v = b2_1[m1];

#pragma unroll
    for (int it = 0; it < 2; ++it) {
      const int r = rh * 8 + it * 4 + rq;
      float xv[8];
#pragma unroll
      for (int k = 0; k < 8; ++k) xv[k] = tile[(j * 8 + k) * 18 + r];
      const float p = slice8(w1a, w1b, b1a, b1b, w2a, w2b, xv);
      if (g == 0) {
        const float v = p + b2v;
        out[(size_t)(rowbase + r) * 2 + j] = 1.f / (1.f + __expf(-v));
      }
    }
  }
}

// ---------------------------------------------------------------------------
extern "C" void kernel_launch(void* const* d_in, const int* in_sizes, int n_in,
                              void* d_out, int out_size, void* d_ws, size_t ws_size,
                              hipStream_t stream) {
  const float* x       = (const float*)d_in[0];
  const int*   task_id = (const int*)  d_in[1];
  const float* emb0    = (const float*)d_in[2];
  const float* emb1    = (const float*)d_in[3];
  const float* emb_out = (const float*)d_in[4];
  const float* W1_0    = (const float*)d_in[5];
  const float* b1_0    = (const float*)d_in[6];
  const float* W2_0    = (const float*)d_in[7];
  const float* b2_0    = (const float*)d_in[8];
  const float* W1_1    = (const float*)d_in[9];
  const float* b1_1    = (const float*)d_in[10];
  const float* W2_1    = (const float*)d_in[11];
  const float* b2_1    = (const float*)d_in[12];

  int* ws = (int*)d_ws;

  route_pre<<<dim3(32, 2), 256, 0, stream>>>(task_id, emb0, emb1, emb_out, ws);
  fused_compute<<<B_SZ / ROWS, 256, 0, stream>>>(x, W1_0, b1_0, W2_0, b2_0,
                                                 W1_1, b1_1, W2_1, b2_1,
                                                 ws, (float*)d_out);
}